// Round 9
// baseline (223.743 us; speedup 1.0000x reference)
//
#include <hip/hip_runtime.h>

// VACF via banded-Gram MFMA, round 18: MEASUREMENT ROUND.
// G[t] = sum_i X[i][:] . X[i+t][:]  (t=0..99), X = [T=10000, C=3000] fp32.
//
// R17 post-mortem: XCD-pinned L2-resident slices changed nothing (188.4 vs
// 186.7). Dead theories so far: HBM BW, occupancy, MLP, DMA window, segment
// fan-out, barrier convoy, L3-read wall fixed by L2 pinning. Invariant:
// global-READ phases pin at 2.2-2.6 TB/s across residency tiers, staging
// mechanisms, patterns, occupancy. No documented latency/BW arithmetic
// produces 70us for 185 MB. Per R17's pre-committed falsifier: this round
// MEASURES instead of guessing.
//  - vacf_probe: bit-identical grid/tile/addresses to fused's staging
//    reads (24 float4/lane, 1880 blocks, 3/CU) but consumed into register
//    accumulators with a never-true guarded store. No cvt, no LDS, no
//    barrier -> unconstrained MLP. Runs BEFORE fused.
//  - vacf_fused: reverted to R16 exactly (best total).
// Attribution: delta-total vs R16's 186.7 = probe duration (+-3us).
// Decision rule (pre-committed):
//   probe ~70-78us (total ~255-265) -> platform read wall for this pattern;
//     next round cuts bytes (bf16 pre-pass reconsidered).
//   probe ~27-32us (total ~213-220) -> fused's load<->cvt<->LDS structure
//     serializes loads (per-store vmcnt); next round decouples them.
//   mid (~45-60) -> partial pattern penalty; check 12000-B row alignment.

#define T_DIM 10000
#define C_DIM 3000
#define W 100
#define MA 256               // A rows per block
#define NA 16                // A subblocks of 16
#define SROWS 384            // staged rows (A + 128-row band)
#define NBB 40               // 40*256 = 10240 >= 10000
#define KS 47                // col-slices of KW (47*64 = 3008 >= 3000)
#define KW 64                // cols per slice (2 MFMA K-chunks)
#define NPART 8              // partial buckets (atomic spread)

typedef __attribute__((ext_vector_type(8))) short short8;    // 8 bf16
typedef __attribute__((ext_vector_type(4))) short short4v;   // 4 bf16
typedef __attribute__((ext_vector_type(4))) float float4v;

__device__ __forceinline__ short f2bf(float f) {   // RNE fp32->bf16 (finite)
    unsigned u = __float_as_uint(f);
    u += 0x7fffu + ((u >> 16) & 1u);
    return (short)(u >> 16);
}

// ---------------------------------------------------------------------------
// PROBE: fused's staging reads, register-consumed. Never-true guarded store
// prevents DCE (compiler cannot prove the sum != magic).
// ---------------------------------------------------------------------------
__global__ __launch_bounds__(256, 3)
void vacf_probe(const float* __restrict__ X, float* __restrict__ sink) {
    const int tid  = threadIdx.x;
    const int ksix = blockIdx.x % KS;
    const int bb   = blockIdx.x / KS;
    const int i0   = bb * MA;
    const int c0   = ksix * KW;

    const int rr = tid >> 4;          // row-in-iter
    const int cl = (tid & 15) * 4;    // col within slice

    float4v acc = {0.f, 0.f, 0.f, 0.f};
    const bool fast = (i0 + SROWS <= T_DIM) && (c0 + KW <= C_DIM);
    if (fast) {
        #pragma unroll
        for (int b = 0; b < 3; ++b) {
            #pragma unroll
            for (int m = 0; m < 8; ++m) {
                const int row = b * 128 + m * 16 + rr;
                acc += *(const float4v*)(X + (size_t)(i0 + row) * C_DIM + c0 + cl);
            }
        }
    } else {
        #pragma unroll
        for (int b = 0; b < 3; ++b) {
            #pragma unroll
            for (int m = 0; m < 8; ++m) {
                const int row = b * 128 + m * 16 + rr;
                const int gr  = i0 + row;
                if (gr < T_DIM && c0 + cl + 4 <= C_DIM)
                    acc += *(const float4v*)(X + (size_t)gr * C_DIM + c0 + cl);
            }
        }
    }
    const float s = acc[0] + acc[1] + acc[2] + acc[3];
    if (s == 1.23456789e38f)                       // never true for this data
        sink[blockIdx.x & 255] = s;
}

// ---------------------------------------------------------------------------
// Fused kernel (bit-identical to R16).
// ---------------------------------------------------------------------------
__global__ __launch_bounds__(256, 3)
void vacf_fused(const float* __restrict__ X, float* __restrict__ partial) {
    const int tid  = threadIdx.x;
    const int lane = tid & 63;
    const int wv   = tid >> 6;
    const int ksix = blockIdx.x % KS;
    const int bb   = blockIdx.x / KS;
    const int i0   = bb * MA;
    const int c0   = ksix * KW;

    __shared__ __align__(16) char lds[SROWS * 128];   // 48 KB
    __shared__ float bins[W];
    if (tid < W) bins[tid] = 0.f;

    const int rr = tid >> 4;          // row-in-iter
    const int cl = (tid & 15) * 4;    // col within slice
    const int sw = ((((cl >> 3) ^ (rr & 7)) << 4) | ((cl & 7) << 1));

    const bool fast = (i0 + SROWS <= T_DIM) && (c0 + KW <= C_DIM);
    if (fast) {
        #pragma unroll
        for (int b = 0; b < 3; ++b) {
            float4v v[8];
            #pragma unroll
            for (int m = 0; m < 8; ++m) {
                const int row = b * 128 + m * 16 + rr;
                v[m] = *(const float4v*)(X + (size_t)(i0 + row) * C_DIM + c0 + cl);
            }
            #pragma unroll
            for (int m = 0; m < 8; ++m) {
                const int row = b * 128 + m * 16 + rr;
                short4v o;
                o[0] = f2bf(v[m][0]); o[1] = f2bf(v[m][1]);
                o[2] = f2bf(v[m][2]); o[3] = f2bf(v[m][3]);
                *(short4v*)&lds[row * 128 + sw] = o;
            }
        }
    } else {
        #pragma unroll
        for (int b = 0; b < 3; ++b) {
            #pragma unroll
            for (int m = 0; m < 8; ++m) {
                const int row = b * 128 + m * 16 + rr;
                const int gr  = i0 + row;
                float4v v = {0.f, 0.f, 0.f, 0.f};
                if (gr < T_DIM && c0 + cl + 4 <= C_DIM)   // 3000%4==0: no straddle
                    v = *(const float4v*)(X + (size_t)gr * C_DIM + c0 + cl);
                short4v o;
                o[0] = f2bf(v[0]); o[1] = f2bf(v[1]);
                o[2] = f2bf(v[2]); o[3] = f2bf(v[3]);
                *(short4v*)&lds[row * 128 + sw] = o;
            }
        }
    }
    __syncthreads();                          // tile ready (and bins init)

    const int n    = lane & 15;
    const int quad = lane >> 4;
    const int d0   = 2 * wv;

    float4v acc0 = {0.f, 0.f, 0.f, 0.f};
    float4v acc1 = {0.f, 0.f, 0.f, 0.f};

    #pragma unroll
    for (int kk = 0; kk < 2; ++kk) {
        const char* lb = lds + n * 128 + (((((kk << 2) | quad)) ^ (n & 7)) << 4);
        short8 fbp = *(const short8*)(lb + d0 * 2048);       // B subblock d0
        #pragma unroll
        for (int a = 0; a < NA; ++a) {
            const short8 fav = *(const short8*)(lb + a * 2048);
            const short8 fbn = *(const short8*)(lb + (d0 + a + 1) * 2048);
            acc0 = __builtin_amdgcn_mfma_f32_16x16x32_bf16(fav, fbp, acc0, 0, 0, 0);
            acc1 = __builtin_amdgcn_mfma_f32_16x16x32_bf16(fav, fbn, acc1, 0, 0, 0);
            fbp = fbn;
        }
    }

    // epilogue: D[m][n] of diagonal d -> lag t = 16d + n - m  (m = quad*4 + p)
    #pragma unroll
    for (int p = 0; p < 4; ++p) {
        const int m  = quad * 4 + p;
        const int t0 = 16 * d0 + n - m;
        if (t0 >= 0 && t0 < W) atomicAdd(&bins[t0], acc0[p]);
        const int t1 = t0 + 16;
        if (t1 >= 0 && t1 < W) atomicAdd(&bins[t1], acc1[p]);
    }
    __syncthreads();
    if (tid < W) atomicAdd(&partial[(blockIdx.x & 7) * W + tid], bins[tid]);
}

__global__ void vacf_scale(const float* __restrict__ partial, float* __restrict__ out) {
    int t = threadIdx.x;
    if (t < W) {
        float s = 0.f;
        #pragma unroll
        for (int b = 0; b < NPART; ++b) s += partial[b * W + t];
        out[t] = s / ((float)(T_DIM - t) * (float)C_DIM);
    }
}

extern "C" void kernel_launch(void* const* d_in, const int* in_sizes, int n_in,
                              void* d_out, int out_size, void* d_ws, size_t ws_size,
                              hipStream_t stream) {
    const float* X = (const float*)d_in[0];
    float* out = (float*)d_out;
    float* ws  = (float*)d_ws;

    hipMemsetAsync(ws, 0, NPART * W * sizeof(float), stream);
    if (ws_size >= (2048 + 256) * sizeof(float)) {
        float* sink = ws + 2048;               // scratch, never actually written
        vacf_probe<<<NBB * KS, 256, 0, stream>>>(X, sink);
    }
    vacf_fused<<<NBB * KS, 256, 0, stream>>>(X, ws);
    vacf_scale<<<1, 128, 0, stream>>>(ws, out);
}

// Round 10
// 184.666 us; speedup vs baseline: 1.2116x; 1.2116x over previous
//
#include <hip/hip_runtime.h>

// VACF via banded-Gram MFMA, round 19: probe-shaped staging.
// G[t] = sum_i X[i][:] . X[i+t][:]  (t=0..99), X = [T=10000, C=3000] fp32.
//
// R18 probe verdict: identical addresses/grid/occupancy at 5.0 TB/s when
// register-consumed (37us) vs 2.6 TB/s in fused's staging (70us). Platform
// read-wall FALSIFIED; structure artifact confirmed: R16 staged in batches
// of 8, so progressive s_waitcnt vmcnt before each cvt+ds_write capped MLP
// at 8 and drained the queue 3x. (Every variant since R9 shared this
// <=8-deep batched shape -- hence the universal 2.2-2.6 TB/s.)
// R19: staging = probe + stores. All 24 float4 loads issued up front
// (v[24], ~96 data VGPRs; cap at 3 waves/SIMD = 170), sched_barrier(0)
// pins loads before the store block, then 24x cvt+ds_write_b64 (first
// waits vmcnt(23), progressive release; ONE drain, 24-deep MLP).
// Everything else bit-identical to R16. Probe removed.
// Predict: fused 70 -> 42-48us, total 186.7 -> ~158-165.
// Falsifier: total ~186 -> compiler had already hoisted; next round reads
// disasm instead of guessing. Spill symptom: regression / WRITE_SIZE >> 1MB
// -> retry 16-deep.

#define T_DIM 10000
#define C_DIM 3000
#define W 100
#define MA 256               // A rows per block
#define NA 16                // A subblocks of 16
#define SROWS 384            // staged rows (A + 128-row band)
#define NBB 40               // 40*256 = 10240 >= 10000
#define KS 47                // col-slices of KW (47*64 = 3008 >= 3000)
#define KW 64                // cols per slice (2 MFMA K-chunks)
#define NPART 8              // partial buckets (atomic spread)

typedef __attribute__((ext_vector_type(8))) short short8;    // 8 bf16
typedef __attribute__((ext_vector_type(4))) short short4v;   // 4 bf16
typedef __attribute__((ext_vector_type(4))) float float4v;

__device__ __forceinline__ short f2bf(float f) {   // RNE fp32->bf16 (finite)
    unsigned u = __float_as_uint(f);
    u += 0x7fffu + ((u >> 16) & 1u);
    return (short)(u >> 16);
}

// ---------------------------------------------------------------------------
// Fused kernel. LDS row = 64 bf16 = 128 B = 8 slots of 16 B; swizzle
// slot ^= row&7. Staging map: iter mm (0..23): row = mm*16 + rr,
// cols cl..cl+3; wave-load = 4 rows x 256 B contiguous segments.
// ---------------------------------------------------------------------------
__global__ __launch_bounds__(256, 3)
void vacf_fused(const float* __restrict__ X, float* __restrict__ partial) {
    const int tid  = threadIdx.x;
    const int lane = tid & 63;
    const int wv   = tid >> 6;
    const int ksix = blockIdx.x % KS;
    const int bb   = blockIdx.x / KS;
    const int i0   = bb * MA;
    const int c0   = ksix * KW;

    __shared__ __align__(16) char lds[SROWS * 128];   // 48 KB
    __shared__ float bins[W];
    if (tid < W) bins[tid] = 0.f;

    const int rr = tid >> 4;          // row-in-iter (0..15)
    const int cl = (tid & 15) * 4;    // col within slice (0..60)
    // swizzled byte offset within the 128-B row (row&7 == rr&7: 16|row-rr)
    const int sw = ((((cl >> 3) ^ (rr & 7)) << 4) | ((cl & 7) << 1));

    const bool fast = (i0 + SROWS <= T_DIM) && (c0 + KW <= C_DIM);
    if (fast) {
        // ---- probe-shaped staging: ALL 24 loads in flight, then stores ----
        float4v v[24];
        #pragma unroll
        for (int mm = 0; mm < 24; ++mm) {
            const int row = mm * 16 + rr;
            v[mm] = *(const float4v*)(X + (size_t)(i0 + row) * C_DIM + c0 + cl);
        }
        __builtin_amdgcn_sched_barrier(0);    // loads stay above the stores
        #pragma unroll
        for (int mm = 0; mm < 24; ++mm) {
            const int row = mm * 16 + rr;
            short4v o;
            o[0] = f2bf(v[mm][0]); o[1] = f2bf(v[mm][1]);
            o[2] = f2bf(v[mm][2]); o[3] = f2bf(v[mm][3]);
            *(short4v*)&lds[row * 128 + sw] = o;
        }
    } else {
        #pragma unroll
        for (int mm = 0; mm < 24; ++mm) {
            const int row = mm * 16 + rr;
            const int gr  = i0 + row;
            float4v v = {0.f, 0.f, 0.f, 0.f};
            if (gr < T_DIM && c0 + cl + 4 <= C_DIM)   // 3000%4==0: no straddle
                v = *(const float4v*)(X + (size_t)gr * C_DIM + c0 + cl);
            short4v o;
            o[0] = f2bf(v[0]); o[1] = f2bf(v[1]);
            o[2] = f2bf(v[2]); o[3] = f2bf(v[3]);
            *(short4v*)&lds[row * 128 + sw] = o;
        }
    }
    __syncthreads();                          // tile ready (and bins init)

    // compute: acc0 = diagonal d0 tiles, acc1 = d0+1.
    const int n    = lane & 15;
    const int quad = lane >> 4;
    const int d0   = 2 * wv;

    float4v acc0 = {0.f, 0.f, 0.f, 0.f};
    float4v acc1 = {0.f, 0.f, 0.f, 0.f};

    #pragma unroll
    for (int kk = 0; kk < 2; ++kk) {
        const char* lb = lds + n * 128 + (((((kk << 2) | quad)) ^ (n & 7)) << 4);
        short8 fbp = *(const short8*)(lb + d0 * 2048);       // B subblock d0
        #pragma unroll
        for (int a = 0; a < NA; ++a) {
            const short8 fav = *(const short8*)(lb + a * 2048);
            const short8 fbn = *(const short8*)(lb + (d0 + a + 1) * 2048);
            acc0 = __builtin_amdgcn_mfma_f32_16x16x32_bf16(fav, fbp, acc0, 0, 0, 0);
            acc1 = __builtin_amdgcn_mfma_f32_16x16x32_bf16(fav, fbn, acc1, 0, 0, 0);
            fbp = fbn;
        }
    }

    // epilogue: D[m][n] of diagonal d -> lag t = 16d + n - m  (m = quad*4 + p)
    #pragma unroll
    for (int p = 0; p < 4; ++p) {
        const int m  = quad * 4 + p;
        const int t0 = 16 * d0 + n - m;
        if (t0 >= 0 && t0 < W) atomicAdd(&bins[t0], acc0[p]);
        const int t1 = t0 + 16;
        if (t1 >= 0 && t1 < W) atomicAdd(&bins[t1], acc1[p]);
    }
    __syncthreads();
    if (tid < W) atomicAdd(&partial[(blockIdx.x & 7) * W + tid], bins[tid]);
}

__global__ void vacf_scale(const float* __restrict__ partial, float* __restrict__ out) {
    int t = threadIdx.x;
    if (t < W) {
        float s = 0.f;
        #pragma unroll
        for (int b = 0; b < NPART; ++b) s += partial[b * W + t];
        out[t] = s / ((float)(T_DIM - t) * (float)C_DIM);
    }
}

extern "C" void kernel_launch(void* const* d_in, const int* in_sizes, int n_in,
                              void* d_out, int out_size, void* d_ws, size_t ws_size,
                              hipStream_t stream) {
    const float* X = (const float*)d_in[0];
    float* out = (float*)d_out;
    float* ws  = (float*)d_ws;

    hipMemsetAsync(ws, 0, NPART * W * sizeof(float), stream);
    vacf_fused<<<NBB * KS, 256, 0, stream>>>(X, ws);
    vacf_scale<<<1, 128, 0, stream>>>(ws, out);
}

// Round 12
// 184.466 us; speedup vs baseline: 1.2129x; 1.0011x over previous
//
#include <hip/hip_runtime.h>

// VACF via banded-Gram MFMA, round 20 RESUBMIT (R20 hit GPUAcquisitionTimeout
// -- infra failure, never ran; no counters, no basis to change design).
// G[t] = sum_i X[i][:] . X[i+t][:]  (t=0..99), X = [T=10000, C=3000] fp32.
//
// R19 post-mortem: 24-deep up-front loads changed nothing (delta -2us);
// MLP theory dead. Correct model: single-shot blocks serialize
// stage(15us/gen) -> compute(7-9us/gen) per generation, and the 3 resident
// blocks run these phases in lockstep -> the CU read path idles during
// every compute phase: 2.45 gens x ~25us = ~62-68us == observed (all
// variants). Probe is fast because blocks END after loading -- reads never
// stop. Fix: keep loads outstanding through compute, structurally.
// R20: persistent grid (768 blocks = 3/CU), each grid-strides ~5 tiles
// (KW=32, MA=256, tile 24KB, dbuf 48KB+bins = 3 blocks/CU exactly).
// Per iteration: issue 12 reg-loads for tile j+1 -> compute tile j
// (33 ds_read_b128 + 32 MFMA/wave) -> cvt+ds_write j+1 to other buffer ->
// ONE __syncthreads. Bonus: D[m][n]->lag map is tile-independent, so accs
// carry across a block's tiles; bins/atomic epilogue once per block.
// ~5 barriers per block TOTAL. Geometry/swizzle/guards = proven R17.
// Predict: fused 68 -> 40-45us, total 184.7 -> ~155-162.
// Falsifier: total ~184 -> lockstep theory wrong; next probe targets
// LDS-write <-> VMEM-return port interference directly.

#define T_DIM 10000
#define C_DIM 3000
#define W 100
#define MA 256               // A rows per tile
#define NA 16                // A subblocks of 16
#define SROWS 384            // staged rows (A + 128-row band)
#define NBB 40               // 40*256 = 10240 >= 10000
#define KS 94                // col-slices (94*32 = 3008 >= 3000)
#define KW 32                // cols per tile (one MFMA K-chunk)
#define NT (KS * NBB)        // 3760 tiles
#define GRID 768             // persistent blocks: 3 per CU x 256 CUs
#define TILE_B (SROWS * 64)  // 24576 B per buffer (bf16)
#define NPART 8              // partial buckets

typedef __attribute__((ext_vector_type(8))) short short8;    // 8 bf16
typedef __attribute__((ext_vector_type(4))) short short4v;   // 4 bf16
typedef __attribute__((ext_vector_type(4))) float float4v;

__device__ __forceinline__ short f2bf(float f) {   // RNE fp32->bf16 (finite)
    unsigned u = __float_as_uint(f);
    u += 0x7fffu + ((u >> 16) & 1u);
    return (short)(u >> 16);
}

// issue the 12 per-lane float4 loads for tile t (guarded at edges)
__device__ __forceinline__ void load_tile(const float* __restrict__ X, int t,
                                          int rr, int cl, float4v* v) {
    const int bb   = t / KS;
    const int ksix = t - bb * KS;
    const int i0   = bb * MA;
    const int c0   = ksix * KW;
    if ((i0 + SROWS <= T_DIM) & (c0 + KW <= C_DIM)) {
        const float* p = X + (size_t)(i0 + rr) * C_DIM + c0 + cl;
        #pragma unroll
        for (int m = 0; m < 12; ++m)
            v[m] = *(const float4v*)(p + (size_t)(m * 32) * C_DIM);
    } else {
        #pragma unroll
        for (int m = 0; m < 12; ++m) {
            const int gr = i0 + m * 32 + rr;
            float4v z = {0.f, 0.f, 0.f, 0.f};
            if (gr < T_DIM && c0 + cl + 4 <= C_DIM)   // col step 4, 3000%4==0
                z = *(const float4v*)(X + (size_t)gr * C_DIM + c0 + cl);
            v[m] = z;
        }
    }
}

// convert + store the 12 loaded float4 into swizzled bf16 LDS buffer
__device__ __forceinline__ void store_tile(char* __restrict__ buf,
                                           int rr, int sw, const float4v* v) {
    #pragma unroll
    for (int m = 0; m < 12; ++m) {
        short4v o;
        o[0] = f2bf(v[m][0]); o[1] = f2bf(v[m][1]);
        o[2] = f2bf(v[m][2]); o[3] = f2bf(v[m][3]);
        *(short4v*)&buf[(m * 32 + rr) * 64 + sw] = o;
    }
}

// ---------------------------------------------------------------------------
// Persistent fused kernel. LDS row = 32 bf16 = 64 B = 4 slots of 16 B,
// phys slot = logical slot ^ ((row>>1)&3)  (R17-verified conflict-free for
// both ds_write_b64 staging and ds_read_b128 fragments).
// ---------------------------------------------------------------------------
__global__ __launch_bounds__(256, 3)
void vacf_fused(const float* __restrict__ X, float* __restrict__ partial) {
    const int tid  = threadIdx.x;
    const int lane = tid & 63;
    const int wv   = tid >> 6;

    __shared__ __align__(16) char lds[2 * TILE_B];   // 48 KB
    __shared__ float bins[W];
    if (tid < W) bins[tid] = 0.f;

    // staging map: iter m: row = m*32 + rr, cols cl..cl+3 (8 rows/wave-load)
    const int rr = tid >> 3;          // 0..31
    const int cl = (tid & 7) * 4;     // 0..28
    const int sw = ((((cl >> 3) ^ ((rr >> 1) & 3)) << 4) | ((cl & 7) << 1));

    // fragment addressing: row n, logical slot quad
    const int n    = lane & 15;
    const int quad = lane >> 4;
    const int d0   = 2 * wv;          // wave's diagonal pair d0, d0+1
    const int fragoff = n * 64 + ((quad ^ ((n >> 1) & 3)) << 4);

    float4v acc0 = {0.f, 0.f, 0.f, 0.f};   // carried across ALL tiles
    float4v acc1 = {0.f, 0.f, 0.f, 0.f};
    float4v v[12];

    // prologue: stage first tile into buffer 0
    int t = blockIdx.x;               // < NT always (768 <= 3760)
    load_tile(X, t, rr, cl, v);
    store_tile(lds, rr, sw, v);
    __syncthreads();

    int cur = 0;
    while (true) {
        const int tn = t + GRID;
        const bool more = (tn < NT);
        if (more) load_tile(X, tn, rr, cl, v);   // loads in flight thru compute
        __builtin_amdgcn_sched_barrier(0);

        // compute tile t from buf[cur]
        {
            const char* lb = lds + cur * TILE_B + fragoff;
            short8 fbp = *(const short8*)(lb + d0 * 1024);
            #pragma unroll
            for (int a = 0; a < NA; ++a) {
                const short8 fav = *(const short8*)(lb + a * 1024);
                const short8 fbn = *(const short8*)(lb + (d0 + a + 1) * 1024);
                acc0 = __builtin_amdgcn_mfma_f32_16x16x32_bf16(fav, fbp, acc0, 0, 0, 0);
                acc1 = __builtin_amdgcn_mfma_f32_16x16x32_bf16(fav, fbn, acc1, 0, 0, 0);
                fbp = fbn;
            }
        }
        __builtin_amdgcn_sched_barrier(0);

        if (more) store_tile(lds + (cur ^ 1) * TILE_B, rr, sw, v);
        __syncthreads();              // writes visible; prev buffer released
        if (!more) break;
        cur ^= 1;
        t = tn;
    }

    // epilogue (once per persistent block):
    // D[m][n] of diagonal d -> lag t = 16d + n - m  (m = quad*4 + p)
    #pragma unroll
    for (int p = 0; p < 4; ++p) {
        const int m  = quad * 4 + p;
        const int t0 = 16 * d0 + n - m;
        if (t0 >= 0 && t0 < W) atomicAdd(&bins[t0], acc0[p]);
        const int t1 = t0 + 16;
        if (t1 >= 0 && t1 < W) atomicAdd(&bins[t1], acc1[p]);
    }
    __syncthreads();
    if (tid < W) atomicAdd(&partial[(blockIdx.x & (NPART - 1)) * W + tid], bins[tid]);
}

__global__ void vacf_scale(const float* __restrict__ partial, float* __restrict__ out) {
    int t = threadIdx.x;
    if (t < W) {
        float s = 0.f;
        #pragma unroll
        for (int b = 0; b < NPART; ++b) s += partial[b * W + t];
        out[t] = s / ((float)(T_DIM - t) * (float)C_DIM);
    }
}

extern "C" void kernel_launch(void* const* d_in, const int* in_sizes, int n_in,
                              void* d_out, int out_size, void* d_ws, size_t ws_size,
                              hipStream_t stream) {
    const float* X = (const float*)d_in[0];
    float* out = (float*)d_out;
    float* ws  = (float*)d_ws;

    hipMemsetAsync(ws, 0, NPART * W * sizeof(float), stream);
    vacf_fused<<<GRID, 256, 0, stream>>>(X, ws);
    vacf_scale<<<1, 128, 0, stream>>>(ws, out);
}